// Round 8
// baseline (118.523 us; speedup 1.0000x reference)
//
#include <hip/hip_runtime.h>
#include <math.h>

#define ALPHA 0.2f
#define LOG2E 1.4426950408889634f

constexpr int B = 32, N = 1024, C = 64;

typedef __attribute__((ext_vector_type(8))) short short8;
typedef __attribute__((ext_vector_type(16))) float floatx16;

// round-half-up bf16
static __device__ __forceinline__ unsigned bfu(float f) {
    return (__float_as_uint(f) + 0x8000u) >> 16;
}
static __device__ __forceinline__ unsigned pk2(float lo, float hi) {
    return ((__float_as_uint(hi) + 0x8000u) & 0xFFFF0000u) |
           ((__float_as_uint(lo) + 0x8000u) >> 16);
}

// ---------------- K1: three block classes -------------------------------
//  [0,1024)    : adj -> 64-bit masks
//  [1024,2048) : exact fp32 s vectors (pre-scaled by log2 e)
//  [2048,2560) : hT(bf16)[b*64+c][j] = (input @ W)^T via 32x32x16 MFMA
__global__ __launch_bounds__(256) void gat_pre(
    const float* __restrict__ input, const float* __restrict__ adj,
    const float* __restrict__ Wm, const float* __restrict__ a,
    unsigned short* __restrict__ hT, float* __restrict__ ssrc,
    float* __restrict__ sdst, unsigned long long* __restrict__ mask64)
{
    const int tid = threadIdx.x, lane = tid & 63, wave = tid >> 6;

    if (blockIdx.x < 1024) {                        // ---- mask blocks ----
        const int mb = blockIdx.x;
#pragma unroll
        for (int t = 0; t < 4; ++t) {
            const int id = mb * 16 + wave * 4 + t;  // 0..16383
            const int i = id >> 4, jc = id & 15;
            const float av = adj[(size_t)i * N + jc * 64 + lane];
            const unsigned long long bal = __ballot(av > 0.5f);
            if (lane == 0) mask64[i * 16 + jc] = bal;
        }
        return;
    }

    if (blockIdx.x < 2048) {                        // ---- s-vector blocks ----
        __shared__ float wa_l[128];
        const int r0 = (blockIdx.x - 1024) * 32;

        if (tid < 128) {                            // wa[k] = sum_c W[k][c]*a[c]
            const int k = tid & 63, half = tid >> 6;
            const float* __restrict__ ar = a + half * 64;
            const float* __restrict__ wr = Wm + k * 64;
            float acc = 0.f;
#pragma unroll
            for (int c4 = 0; c4 < 16; ++c4) {
                const float4 wv = *(const float4*)&wr[c4 * 4];
                const float4 av = *(const float4*)&ar[c4 * 4];
                acc = fmaf(wv.x, av.x, fmaf(wv.y, av.y, fmaf(wv.z, av.z, fmaf(wv.w, av.w, acc))));
            }
            wa_l[half * 64 + k] = acc;
        }
        __syncthreads();

        const int row = r0 + (tid >> 3), seg = tid & 7;
        const float4 x0 = *(const float4*)&input[(size_t)row * 64 + seg * 8];
        const float4 x1 = *(const float4*)&input[(size_t)row * 64 + seg * 8 + 4];
        float vs = 0.f, vd = 0.f;
        const float4 w0 = *(const float4*)&wa_l[seg * 8];
        const float4 w1 = *(const float4*)&wa_l[seg * 8 + 4];
        const float4 d0 = *(const float4*)&wa_l[64 + seg * 8];
        const float4 d1 = *(const float4*)&wa_l[64 + seg * 8 + 4];
        vs = fmaf(x0.x, w0.x, fmaf(x0.y, w0.y, fmaf(x0.z, w0.z, fmaf(x0.w, w0.w, vs))));
        vs = fmaf(x1.x, w1.x, fmaf(x1.y, w1.y, fmaf(x1.z, w1.z, fmaf(x1.w, w1.w, vs))));
        vd = fmaf(x0.x, d0.x, fmaf(x0.y, d0.y, fmaf(x0.z, d0.z, fmaf(x0.w, d0.w, vd))));
        vd = fmaf(x1.x, d1.x, fmaf(x1.y, d1.y, fmaf(x1.z, d1.z, fmaf(x1.w, d1.w, vd))));
        vs += __shfl_xor(vs, 1, 64); vd += __shfl_xor(vd, 1, 64);
        vs += __shfl_xor(vs, 2, 64); vd += __shfl_xor(vd, 2, 64);
        vs += __shfl_xor(vs, 4, 64); vd += __shfl_xor(vd, 4, 64);
        if (seg == 0) { ssrc[row] = vs * LOG2E; sdst[row] = vd * LOG2E; }
        return;
    }

    // ---- hT blocks: 512 blocks = (b, jseg of 64); wave = (c-half, j-sub32) --
    {
        const int hb = blockIdx.x - 2048;           // 0..511
        const int b  = hb >> 4;
        const int jseg = (hb & 15) * 64;
        const int wc = wave & 1, jsub = wave >> 1;
        const int jb = jseg + jsub * 32;
        const int n32 = lane & 31, kh = lane >> 5;

        // A = W^T: frag element e = W[(q*16+kh*8+e)*64 + wc*32+n32]
        short8 wfr[4];
#pragma unroll
        for (int q = 0; q < 4; ++q)
#pragma unroll
            for (int e = 0; e < 8; ++e)
                wfr[q][e] = (short)bfu(Wm[(q * 16 + kh * 8 + e) * 64 + wc * 32 + n32]);

        const float* __restrict__ inb = input + (size_t)b * 1024 * 64;
        floatx16 acc = {};
#pragma unroll
        for (int q = 0; q < 4; ++q) {
            const float4 x0 = *(const float4*)&inb[(size_t)(jb + n32) * 64 + q * 16 + kh * 8];
            const float4 x1 = *(const float4*)&inb[(size_t)(jb + n32) * 64 + q * 16 + kh * 8 + 4];
            union { uint4 u; short8 s; } bf;
            bf.u.x = pk2(x0.x, x0.y); bf.u.y = pk2(x0.z, x0.w);
            bf.u.z = pk2(x1.x, x1.y); bf.u.w = pk2(x1.z, x1.w);
            acc = __builtin_amdgcn_mfma_f32_32x32x16_bf16(wfr[q], bf.s, acc, 0, 0, 0);
        }
#pragma unroll
        for (int r = 0; r < 16; ++r) {
            const int rc = (r & 3) + 8 * (r >> 2) + 4 * kh;   // c offset
            hT[((size_t)(b * 64 + wc * 32 + rc)) * 1024 + jb + n32] = (unsigned short)bfu(acc[r]);
        }
    }
}

// ---------------- K2: barrier-free fused softmax + PV (32x32x16 MFMA) ------
// Block = (b, i-tile 32). Wave = j-quarter (256 j), covers ALL 64 c via two
// accumulators -> p computed exactly once per (i,j). One barrier, LDS merge.
__global__ __launch_bounds__(256, 4) void gat_attn(
    const unsigned short* __restrict__ hTg, const float* __restrict__ ssrc,
    const float* __restrict__ sdst, const unsigned long long* __restrict__ mask64,
    float* __restrict__ out)
{
    __shared__ __align__(16) float acc_l[4][32 * 68];   // 4 x 8.5 KB (padded rows)
    __shared__ float psum_l[4][32];

    const int tid = threadIdx.x, lane = tid & 63, wave = tid >> 6;
    const int b  = blockIdx.x & 31;
    const int i0 = (blockIdx.x >> 5) * 32;
    const int wj = wave;                            // j-quarter
    const int n32 = lane & 31, kh = lane >> 5;

    const float ssq = ssrc[b * N + i0 + n32];       // A row this lane owns
    const float* __restrict__ sdb = sdst + b * N;
    const unsigned short* __restrict__ hT0 = hTg + ((size_t)(b * 64 + n32)) * 1024;
    const unsigned short* __restrict__ hT1 = hT0 + 32 * 1024;
    const unsigned long long* __restrict__ mrow = mask64 + (size_t)(i0 + n32) * 16;

    floatx16 acc0 = {}, acc1 = {};
    float psacc = 0.f;

    for (int t = 0; t < 4; ++t) {
        const int jt = wj * 4 + t;
        const int jb = jt * 64;

        short8 bf0[4], bf1[4];
        float4 sa[4], sb[4];
#pragma unroll
        for (int q = 0; q < 4; ++q) {
            bf0[q] = *(const short8*)&hT0[jb + q * 16 + kh * 8];   // c 0..31
            bf1[q] = *(const short8*)&hT1[jb + q * 16 + kh * 8];   // c 32..63
            sa[q]  = *(const float4*)&sdb[jb + q * 16 + kh * 8];
            sb[q]  = *(const float4*)&sdb[jb + q * 16 + kh * 8 + 4];
        }
        const uint2 mw = *(const uint2*)&mrow[jt];

#pragma unroll
        for (int q = 0; q < 4; ++q) {
            const unsigned mword = (q < 2) ? mw.x : mw.y;
            const unsigned msh = mword >> ((q & 1) * 16 + kh * 8);
            const float sv[8] = {sa[q].x, sa[q].y, sa[q].z, sa[q].w,
                                 sb[q].x, sb[q].y, sb[q].z, sb[q].w};
            float p[8];
#pragma unroll
            for (int e = 0; e < 8; ++e) {
                float tv = ssq + sv[e];
                tv = fmaxf(tv, ALPHA * tv);                  // leaky-relu (log2 domain)
                tv = ((msh >> e) & 1u) ? tv : -200.f;        // mask -> exp2 = 0
                p[e] = exp2f(tv);
                psacc += p[e];
            }
            union { uint4 u; short8 s; } af;
            af.u.x = pk2(p[0], p[1]); af.u.y = pk2(p[2], p[3]);
            af.u.z = pk2(p[4], p[5]); af.u.w = pk2(p[6], p[7]);
            acc0 = __builtin_amdgcn_mfma_f32_32x32x16_bf16(af.s, bf0[q], acc0, 0, 0, 0);
            acc1 = __builtin_amdgcn_mfma_f32_32x32x16_bf16(af.s, bf1[q], acc1, 0, 0, 0);
        }
    }

    // lane psacc covers row i=n32 over this wave's j-quarter (both kh halves)
    psacc += __shfl_xor(psacc, 32, 64);
    if (lane < 32) psum_l[wave][lane] = psacc;

#pragma unroll
    for (int r = 0; r < 16; ++r) {
        const int row = (r & 3) + 8 * (r >> 2) + 4 * kh;     // C/D row map
        acc_l[wave][row * 68 + n32]      = acc0[r];
        acc_l[wave][row * 68 + 32 + n32] = acc1[r];
    }
    __syncthreads();

    // epilogue: thread -> (row i = tid>>3, c-octet = tid&7)
    {
        const int i = tid >> 3, c8 = (tid & 7) * 8;
        float4 u0 = {0.f,0.f,0.f,0.f}, u1 = {0.f,0.f,0.f,0.f};
#pragma unroll
        for (int w = 0; w < 4; ++w) {
            const float4 v0 = *(const float4*)&acc_l[w][i * 68 + c8];
            const float4 v1 = *(const float4*)&acc_l[w][i * 68 + c8 + 4];
            u0.x += v0.x; u0.y += v0.y; u0.z += v0.z; u0.w += v0.w;
            u1.x += v1.x; u1.y += v1.y; u1.z += v1.z; u1.w += v1.w;
        }
        const float ps = psum_l[0][i] + psum_l[1][i] + psum_l[2][i] + psum_l[3][i];
        const float inv = 1.f / ps;
        float o[8] = {u0.x * inv, u0.y * inv, u0.z * inv, u0.w * inv,
                      u1.x * inv, u1.y * inv, u1.z * inv, u1.w * inv};
        float4 w0, w1;
        w0.x = o[0] > 0.f ? o[0] : __expf(o[0]) - 1.f;
        w0.y = o[1] > 0.f ? o[1] : __expf(o[1]) - 1.f;
        w0.z = o[2] > 0.f ? o[2] : __expf(o[2]) - 1.f;
        w0.w = o[3] > 0.f ? o[3] : __expf(o[3]) - 1.f;
        w1.x = o[4] > 0.f ? o[4] : __expf(o[4]) - 1.f;
        w1.y = o[5] > 0.f ? o[5] : __expf(o[5]) - 1.f;
        w1.z = o[6] > 0.f ? o[6] : __expf(o[6]) - 1.f;
        w1.w = o[7] > 0.f ? o[7] : __expf(o[7]) - 1.f;
        float* dst = out + ((size_t)(b * N + i0 + i)) * 64 + c8;
        *(float4*)dst = w0;
        *(float4*)(dst + 4) = w1;
    }
}

extern "C" void kernel_launch(void* const* d_in, const int* in_sizes, int n_in,
                              void* d_out, int out_size, void* d_ws, size_t ws_size,
                              hipStream_t stream) {
    const float* input = (const float*)d_in[0];
    const float* adj   = (const float*)d_in[1];
    const float* Wm    = (const float*)d_in[2];
    const float* a     = (const float*)d_in[3];
    float* out = (float*)d_out;

    char* ws = (char*)d_ws;
    unsigned short* hT = (unsigned short*)ws;                                      // 4 MB
    float* ssrc = (float*)(ws + 4194304);                                          // 128 KB
    float* sdst = (float*)(ws + 4194304 + 131072);                                 // 128 KB
    unsigned long long* mask64 = (unsigned long long*)(ws + 4194304 + 2 * 131072); // 128 KB

    gat_pre<<<2560, 256, 0, stream>>>(input, adj, Wm, a, hT, ssrc, sdst, mask64);
    gat_attn<<<1024, 256, 0, stream>>>(hT, ssrc, sdst, mask64, out);
}